// Round 8
// baseline (132.097 us; speedup 1.0000x reference)
//
#include <hip/hip_runtime.h>

#define N 1024
#define D 256
#define GH 64   // g's (d-pairs) per half; D/2 = 128 g's total, split in 2

// ---------------- prep ----------------
// 128 blocks x 8 rows, LDS-staged transpose; ALSO zeroes d_out (pair kernel
// accumulates into out with atomics, and the harness poisons out each call).
#define RI 8
#define LDW 260

__global__ __launch_bounds__(256) void prep3(
    const float* __restrict__ muX, const float* __restrict__ ls,
    float2* __restrict__ msT2, float4* __restrict__ out4) {
  const int i0 = blockIdx.x * RI;
  const int t = threadIdx.x;
  // zero 32KB of out per block (128 blocks x 256 thr x 8 float4 = 4MB)
#pragma unroll
  for (int u = 0; u < 8; ++u)
    out4[(size_t)blockIdx.x * 2048 + u * 256 + t] =
        make_float4(0.f, 0.f, 0.f, 0.f);
  __shared__ float smu[RI][LDW];
  __shared__ float ssg[RI][LDW];
  __shared__ float sred[RI][32];
  __shared__ float rden[RI];
  const float4* mu4 = (const float4*)(muX + (size_t)i0 * D);
  const float4* ls4 = (const float4*)(ls + (size_t)i0 * D);
#pragma unroll
  for (int u = 0; u < 2; ++u) {
    const int idx = u * 256 + t;
    const int row = idx >> 6, c4 = idx & 63;
    const float4 v = mu4[idx];
    *(float4*)&smu[row][c4 * 4] = v;
    const float4 e = ls4[idx];
    float4 x;
    x.x = __expf(e.x) + 5e-11f; x.y = __expf(e.y) + 5e-11f;  // eps folded
    x.z = __expf(e.z) + 5e-11f; x.w = __expf(e.w) + 5e-11f;
    *(float4*)&ssg[row][c4 * 4] = x;
  }
  __syncthreads();
  {
    const int r = t >> 5, q = t & 31;
    float s = 0.f;
#pragma unroll
    for (int k = 0; k < 8; ++k) {
      const float v = smu[r][q + 32 * k];
      s = fmaf(v, v, s);
    }
    sred[r][q] = s;
  }
  __syncthreads();
  if (t < RI) {
    float tot = 0.f;
    for (int u = 0; u < 32; ++u) tot += sred[t][u];
    rden[t] = 1.0f / fmaxf(sqrtf(tot), 1e-12f);  // F.normalize eps
  }
  __syncthreads();
#pragma unroll
  for (int pass = 0; pass < 8; ++pass) {
    const int f = pass * 256 + t;
    const int b = f & 1, il = (f >> 1) & 7, g = f >> 4;
    const int d = 2 * g + b;
    msT2[((size_t)g * N + i0 + il) * 2 + b] =
        make_float2(smu[il][d] * rden[il], ssg[il][d]);
  }
}

// ---------------- pair ----------------
// R5's proven per-wave structure (uniform-i s_loads, per-lane j float4,
// unroll 4, ln via running product), but the d-range is SPLIT IN HALF:
// grid 4608 blocks = 9216 waves = 9/SIMD (R5 had 2.15/SIMD — grid-limited
// occupancy was the duty cap: each wave idles ~110cy/iter on L1 latency at
// ~26% duty; 9 waves/SIMD fully cover it). Halves are additive (acc and
// log2-partials both sum), accumulated with fp32 HW atomics into zeroed out.
__global__ __launch_bounds__(128) void pair_kernel(
    const float4* __restrict__ msT4, float* __restrict__ out) {
  int L = blockIdx.x;
  const int half = L & 1;
  L >>= 1;  // triangular tile id 0..2303
  int js = 0, base = 0;  // slab js has 64*(js+1) row-tiles of 2 rows
  while (L >= base + 64 * (js + 1)) { base += 64 * (js + 1); ++js; }
  const int ib = L - base;
  const int j0 = js * 128, i0 = ib * 2;
  const bool diag = (ib >= js * 64);
  const int j = j0 + threadIdx.x;

  const float4* __restrict__ ph = msT4 + (size_t)(half * GH) * N;

  float acc[2] = {0.f, 0.f};
  float p[2] = {1.f, 1.f};
  int ea[2] = {0, 0};

#pragma unroll 4
  for (int gg = 0; gg < GH; ++gg) {
    const float4 jv = ph[(size_t)gg * N + j];
#pragma unroll
    for (int k = 0; k < 2; ++k) {
      const float4 iv = ph[(size_t)gg * N + i0 + k];  // uniform -> s_load
      {
        const float sv = iv.y + jv.y;
        const float t0 = iv.x - jv.x;
        acc[k] = fmaf(t0 * t0, __builtin_amdgcn_rcpf(sv), acc[k]);
        p[k] *= sv;
      }
      {
        const float sv = iv.w + jv.w;
        const float t0 = iv.z - jv.z;
        acc[k] = fmaf(t0 * t0, __builtin_amdgcn_rcpf(sv), acc[k]);
        p[k] *= sv;
      }
    }
    if (gg & 1) {  // strip exponent every 4 d's (|log2 s|<~9 -> safe)
#pragma unroll
      for (int k = 0; k < 2; ++k) {
        const int bb = __float_as_int(p[k]);
        ea[k] += bb >> 23;
        p[k] = __int_as_float((bb & 0x007fffff) | 0x3f800000);
      }
    }
  }

  constexpr float LN2 = 0.6931471805599453f;
  float v[2];
#pragma unroll
  for (int k = 0; k < 2; ++k) {
    const float lg2 = (float)(ea[k] - 127 * (GH / 2)) + __log2f(p[k]);
    v[k] = -(acc[k] + LN2 * lg2);  // this half's partial
  }

  if (!diag) {  // strictly-upper tile: direct + mirror, both atomic
    atomicAdd(&out[(size_t)i0 * N + j], v[0]);
    atomicAdd(&out[(size_t)(i0 + 1) * N + j], v[1]);
    atomicAdd(&out[(size_t)j * N + i0], v[0]);
    atomicAdd(&out[(size_t)j * N + i0 + 1], v[1]);
  } else {  // diagonal tile: per-element masks
#pragma unroll
    for (int k = 0; k < 2; ++k) {
      const int i = i0 + k;
      if (j >= i) atomicAdd(&out[(size_t)i * N + j], v[k]);
      if (j > i) atomicAdd(&out[(size_t)j * N + i], v[k]);
    }
  }
}

extern "C" void kernel_launch(void* const* d_in, const int* in_sizes, int n_in,
                              void* d_out, int out_size, void* d_ws, size_t ws_size,
                              hipStream_t stream) {
  const float* muX = (const float*)d_in[0];
  const float* ls  = (const float*)d_in[1];
  float* out = (float*)d_out;
  float2* msT2 = (float2*)d_ws;  // [D/2][N] packed (mu,sig,mu,sig) = 2 MB
  prep3<<<dim3(N / RI), dim3(256), 0, stream>>>(muX, ls, msT2, (float4*)out);
  const int nblocks = 2 * 64 * (8 * 9 / 2);  // 2 halves x 2304 tri tiles
  pair_kernel<<<dim3(nblocks), dim3(128), 0, stream>>>((const float4*)msT2,
                                                       out);
}

// Round 9
// 96.492 us; speedup vs baseline: 1.3690x; 1.3690x over previous
//
#include <hip/hip_runtime.h>

#define N 1024
#define D 256

// ---------------- prep ----------------
// 128 blocks x 8 rows, LDS-staged: coalesced float4 global loads, padded-LDS
// transpose, coalesced 8B stores.
#define RI 8
#define LDW 260

__global__ __launch_bounds__(256) void prep3(
    const float* __restrict__ muX, const float* __restrict__ ls,
    float2* __restrict__ msT2) {
  const int i0 = blockIdx.x * RI;
  const int t = threadIdx.x;
  __shared__ float smu[RI][LDW];
  __shared__ float ssg[RI][LDW];
  __shared__ float sred[RI][32];
  __shared__ float rden[RI];
  const float4* mu4 = (const float4*)(muX + (size_t)i0 * D);
  const float4* ls4 = (const float4*)(ls + (size_t)i0 * D);
#pragma unroll
  for (int u = 0; u < 2; ++u) {
    const int idx = u * 256 + t;
    const int row = idx >> 6, c4 = idx & 63;
    const float4 v = mu4[idx];
    *(float4*)&smu[row][c4 * 4] = v;
    const float4 e = ls4[idx];
    float4 x;
    x.x = __expf(e.x) + 5e-11f; x.y = __expf(e.y) + 5e-11f;  // eps folded
    x.z = __expf(e.z) + 5e-11f; x.w = __expf(e.w) + 5e-11f;
    *(float4*)&ssg[row][c4 * 4] = x;
  }
  __syncthreads();
  {
    const int r = t >> 5, q = t & 31;
    float s = 0.f;
#pragma unroll
    for (int k = 0; k < 8; ++k) {
      const float v = smu[r][q + 32 * k];
      s = fmaf(v, v, s);
    }
    sred[r][q] = s;
  }
  __syncthreads();
  if (t < RI) {
    float tot = 0.f;
    for (int u = 0; u < 32; ++u) tot += sred[t][u];
    rden[t] = 1.0f / fmaxf(sqrtf(tot), 1e-12f);  // F.normalize eps
  }
  __syncthreads();
#pragma unroll
  for (int pass = 0; pass < 8; ++pass) {
    const int f = pass * 256 + t;
    const int b = f & 1, il = (f >> 1) & 7, g = f >> 4;
    const int d = 2 * g + b;
    msT2[((size_t)g * N + i0 + il) * 2 + b] =
        make_float2(smu[il][d] * rden[il], ssg[il][d]);
  }
}

// ---------------- pair ----------------
// R5's structure (triangular 2x128 tiles, uniform-i s_loads, per-lane j
// float4, unroll 4, ln via running product) + R9's XCD-AWARE SWIZZLE:
// hardware dispatches blockIdx round-robin across 8 XCDs, so R5's consecutive
// tile ids scattered every j-strip onto every XCD -> each 4MB per-XCD L2
// thrashed the full 2MB msT (FETCH_SIZE 9.2MB on a 2MB operand; hot loads at
// ~900cy HBM latency -> 26% per-wave duty). Remap B -> L=(B%8)*288+B/8 so
// each XCD owns a CONTIGUOUS run of 288 tiles (<=3 j-strips ~ 0.75MB) that
// stays L2-resident.
__global__ __launch_bounds__(128) void pair_kernel(
    const float4* __restrict__ msT4, float* __restrict__ out) {
  const int B = blockIdx.x;
  int L = (B & 7) * 288 + (B >> 3);  // invert round-robin: XCD = B%8 owns
                                     // tiles [288*xcd, 288*(xcd+1))
  int js = 0, base = 0;  // slab js has 64*(js+1) row-tiles of 2 rows
  while (L >= base + 64 * (js + 1)) { base += 64 * (js + 1); ++js; }
  const int ib = L - base;
  const int j0 = js * 128, i0 = ib * 2;
  const bool diag = (ib >= js * 64);  // tile straddles the diagonal
  const int j = j0 + threadIdx.x;

  float acc[2] = {0.f, 0.f};
  float p[2] = {1.f, 1.f};
  int ea[2] = {0, 0};

#pragma unroll 4
  for (int g = 0; g < D / 2; ++g) {
    const float4 jv = msT4[(size_t)g * N + j];
#pragma unroll
    for (int k = 0; k < 2; ++k) {
      const float4 iv = msT4[(size_t)g * N + i0 + k];  // uniform -> s_load
      {
        const float sv = iv.y + jv.y;
        const float t0 = iv.x - jv.x;
        acc[k] = fmaf(t0 * t0, __builtin_amdgcn_rcpf(sv), acc[k]);
        p[k] *= sv;
      }
      {
        const float sv = iv.w + jv.w;
        const float t0 = iv.z - jv.z;
        acc[k] = fmaf(t0 * t0, __builtin_amdgcn_rcpf(sv), acc[k]);
        p[k] *= sv;
      }
    }
    if (g & 1) {  // strip exponent every 4 d's (|log2 s|<~9 -> safe)
#pragma unroll
      for (int k = 0; k < 2; ++k) {
        const int bb = __float_as_int(p[k]);
        ea[k] += bb >> 23;
        p[k] = __int_as_float((bb & 0x007fffff) | 0x3f800000);
      }
    }
  }

  constexpr float LN2 = 0.6931471805599453f;
  float v[2];
#pragma unroll
  for (int k = 0; k < 2; ++k) {
    const float lg2 = (float)(ea[k] - 127 * (D / 4)) + __log2f(p[k]);
    v[k] = -(acc[k] + LN2 * lg2);
  }

  if (!diag) {  // strictly-upper tile: unmasked direct + mirror writes
    out[(size_t)i0 * N + j] = v[0];
    out[(size_t)(i0 + 1) * N + j] = v[1];
    *(float2*)(out + (size_t)j * N + i0) = make_float2(v[0], v[1]);
  } else {  // diagonal tile: per-element masks
#pragma unroll
    for (int k = 0; k < 2; ++k) {
      const int i = i0 + k;
      if (j >= i) out[(size_t)i * N + j] = v[k];
      if (j > i) out[(size_t)j * N + i] = v[k];
    }
  }
}

extern "C" void kernel_launch(void* const* d_in, const int* in_sizes, int n_in,
                              void* d_out, int out_size, void* d_ws, size_t ws_size,
                              hipStream_t stream) {
  const float* muX = (const float*)d_in[0];
  const float* ls  = (const float*)d_in[1];
  float* out = (float*)d_out;
  float2* msT2 = (float2*)d_ws;  // [D/2][N] packed (mu,sig,mu,sig) = 2 MB
  prep3<<<dim3(N / RI), dim3(256), 0, stream>>>(muX, ls, msT2);
  const int nblocks = 64 * (8 * 9 / 2);  // 2304 = 8 XCD chunks x 288 tiles
  pair_kernel<<<dim3(nblocks), dim3(128), 0, stream>>>((const float4*)msT2,
                                                       out);
}